// Round 2
// baseline (249.455 us; speedup 1.0000x reference)
//
#include <hip/hip_runtime.h>

#define T_STEPS 2000
#define BATCH   2048
#define TPAD    2048   // padded time stride for ws layout [b][t]
#define TT      32     // t-outputs per thread in conv pass

// ---------------- Pass 1: currents convolution ----------------
// x''[t,b] = (sum_j a[j]*c[t-63+j, b] - b_act) / max_current, written to xt[b][t]
__global__ __launch_bounds__(256) void conv_kernel(
    const float* __restrict__ currents, const float* __restrict__ a,
    const float* __restrict__ b_act, const float* __restrict__ max_current,
    float* __restrict__ xt)
{
    __shared__ float sa[64];
    int tid = threadIdx.x;
    if (tid < 64) sa[tid] = a[tid];
    __syncthreads();

    int b  = blockIdx.y * 256 + tid;
    int t0 = blockIdx.x * TT;

    float w[TT + 63];
#pragma unroll
    for (int k = 0; k < TT + 63; ++k) {
        int tau = t0 - 63 + k;
        w[k] = (tau >= 0 && tau < T_STEPS) ? currents[(long)tau * BATCH + b] : 0.0f;
    }

    float acc[TT];
#pragma unroll
    for (int i = 0; i < TT; ++i) acc[i] = 0.0f;

#pragma unroll
    for (int j = 0; j < 64; ++j) {
        float aj = sa[j];
#pragma unroll
        for (int i = 0; i < TT; ++i)
            acc[i] = fmaf(aj, w[i + j], acc[i]);
    }

    float ba     = b_act[0];
    float inv_mc = 1.0f / max_current[0];
#pragma unroll
    for (int i = 0; i < TT; ++i) {
        int t = t0 + i;
        if (t < T_STEPS) xt[(long)b * TPAD + t] = (acc[i] - ba) * inv_mc;
    }
}

// ---------------- Pass 2: sequential recurrence, one wave per batch --------
// Scatter-ring: lane L owns future step s with s == L (mod 64). acc holds
// x''[s] + sum of beta[d]*f[s-d] contributions so far; at step t, lane t&63
// is complete -> readlane. beta[d] = (1000/mc)*b_lag[64-d]; gamma[i]=beta[i+1].
__global__ __launch_bounds__(256) void recur_kernel(
    const float* __restrict__ xt, const float* __restrict__ b_lag,
    const float* __restrict__ poly_coeff, const float* __restrict__ max_current,
    const float* __restrict__ max_firing_rate, float* __restrict__ out)
{
    __shared__ float g2[128];  // gamma duplicated: g2[j] = gamma[j & 63]
    int tid = threadIdx.x;
    float mc    = max_current[0];
    float scale = 1000.0f / mc;
    if (tid < 128) {
        int i = tid & 63;
        g2[tid] = scale * b_lag[63 - i];   // gamma[i] = scale*b_lag[63-i]
    }
    __syncthreads();

    int lane = tid & 63;
    int wid  = tid >> 6;
    int b    = blockIdx.x * 4 + wid;

    // tanh(p) = 1 - 2/(exp2(K2*p)+1); fold K2=2*log2(e) into squared coeffs
    const float K2 = 2.8853900817779268f;
    float c0 = poly_coeff[0], c1 = poly_coeff[1], c2 = poly_coeff[2], c3 = poly_coeff[3];
    float k0 = K2 * c0 * c0, k1 = K2 * c1 * c1, k2 = K2 * c2 * c2, k3 = K2 * c3 * c3;
    float M  = max_firing_rate[0];
    float m2 = -2.0f * M;

    const float* xrow = xt + (long)b * TPAD;
    float acc = xrow[lane];      // chunk 0: acc starts as x''[lane] (y history = 0)
    float fv  = 0.0f;
    float* outcol = out + b;

    const int NCHUNK = (T_STEPS + 63) / 64;
    for (int chunk = 0; chunk < NCHUNK; ++chunk) {
        int t0 = chunk * 64;
        int tn = t0 + 64 + lane;                       // next chunk's x'' for ring reset
        float xn = (tn < T_STEPS) ? xrow[tn] : 0.0f;
        int ns = min(64, T_STEPS - t0);

        for (int s = 0; s < ns; ++s) {
            // u = x''[t] + y'[t], complete in lane s
            float u = __builtin_bit_cast(float,
                        __builtin_amdgcn_readlane(__builtin_bit_cast(int, acc), s));
            // p = K2 * poly(u), Estrin depth 2
            float u2 = u * u;
            float a1 = fmaf(u, k1, k0);
            float a2 = fmaf(u, k3, k2);
            float p  = fmaf(u2, a2, a1);
            p = fminf(p, 126.0f);                      // exp2 overflow guard
            float e = __builtin_amdgcn_exp2f(p);       // e^(2*poly), <= 2^126 (finite)
            float d = e + 1.0f;
            float r = __builtin_amdgcn_rcpf(d);
            // f = relu(M*tanh) = max(M - 2M/(e+1), 0)  -- overflow-free form
            float f = fmaxf(fmaf(m2, r, M), 0.0f);

            // per-lane coefficient gamma[(lane - t - 1) & 63] = g2[lane + 63 - s]
            float coef = g2[lane + 63 - s];
            bool own = (lane == s);
            acc = own ? xn : acc;                      // ring reset to x''[t+64]
            fv  = own ? f  : fv;                       // stash output
            acc = fmaf(coef, f, acc);
        }

        int tw = t0 + lane;
        if (tw < T_STEPS) outcol[(long)tw * BATCH] = fv;
    }
}

extern "C" void kernel_launch(void* const* d_in, const int* in_sizes, int n_in,
                              void* d_out, int out_size, void* d_ws, size_t ws_size,
                              hipStream_t stream) {
    const float* currents   = (const float*)d_in[0];
    const float* a          = (const float*)d_in[1];
    const float* b_lag      = (const float*)d_in[2];
    const float* poly_coeff = (const float*)d_in[3];
    const float* b_act      = (const float*)d_in[4];
    const float* mc         = (const float*)d_in[5];
    const float* mfr        = (const float*)d_in[6];
    float* out = (float*)d_out;
    float* xt  = (float*)d_ws;   // needs BATCH*TPAD*4 = 16.78 MB

    conv_kernel<<<dim3((T_STEPS + TT - 1) / TT, BATCH / 256), 256, 0, stream>>>(
        currents, a, b_act, mc, xt);
    recur_kernel<<<BATCH / 4, 256, 0, stream>>>(
        xt, b_lag, poly_coeff, mc, mfr, out);
}